// Round 8
// baseline (1546.550 us; speedup 1.0000x reference)
//
#include <hip/hip_runtime.h>
#include <math.h>

#define DIM 128
#define NRBF 64
#define K1 320          // dim + rbf + dim
#define ET 64           // edges per block
#define NT 64           // nodes per block

typedef __attribute__((ext_vector_type(8))) _Float16 f16x8;
typedef __attribute__((ext_vector_type(4))) float f32x4;

__device__ __forceinline__ float sigmoidf_(float v) { return 1.0f / (1.0f + __expf(-v)); }
__device__ __forceinline__ float swishf_(float v)   { return v * sigmoidf_(v); }

__device__ __forceinline__ f16x8 cvt8(float4 a, float4 b) {
    f16x8 v;
    v[0] = (_Float16)a.x; v[1] = (_Float16)a.y; v[2] = (_Float16)a.z; v[3] = (_Float16)a.w;
    v[4] = (_Float16)b.x; v[5] = (_Float16)b.y; v[6] = (_Float16)b.z; v[7] = (_Float16)b.w;
    return v;
}

// ---------------------------------------------------------------------------
// Prep: x (f32) -> f16
// ---------------------------------------------------------------------------
__global__ void cvt_x_kernel(const float* __restrict__ in, _Float16* __restrict__ out,
                             int n8) {
    int i = blockIdx.x * blockDim.x + threadIdx.x;
    if (i >= n8) return;
    const float4* p = (const float4*)in + 2 * (size_t)i;
    float4 a = p[0], b = p[1];
    ((f16x8*)out)[i] = cvt8(a, b);
}

// Prep: weight [K][128] f32 -> transposed f16 [128][K]
__global__ void wT_kernel(const float* __restrict__ w, _Float16* __restrict__ wt, int K) {
    int k = blockIdx.x * 64 + threadIdx.x;
    int n = blockIdx.y;
    if (k < K) wt[(size_t)n * K + k] = (_Float16)w[(size_t)k * DIM + n];
}

// ---------------------------------------------------------------------------
// Counting sort of edges by destination col.
// ---------------------------------------------------------------------------
__global__ void hist_kernel(const int* __restrict__ col, unsigned* __restrict__ hist,
                            unsigned* __restrict__ epos, int E) {
    int e = blockIdx.x * 256 + threadIdx.x;
    if (e < E) epos[e] = atomicAdd(&hist[col[e]], 1u);
}

__global__ void scan_blocks(unsigned* __restrict__ hist, unsigned* __restrict__ bsum, int N) {
    __shared__ unsigned s[256];
    int i = blockIdx.x * 256 + threadIdx.x;
    unsigned v = (i < N) ? hist[i] : 0u;
    s[threadIdx.x] = v;
    __syncthreads();
    for (int off = 1; off < 256; off <<= 1) {
        unsigned t = (threadIdx.x >= off) ? s[threadIdx.x - off] : 0u;
        __syncthreads();
        s[threadIdx.x] += t;
        __syncthreads();
    }
    if (i < N) hist[i] = s[threadIdx.x] - v;        // exclusive within block
    if (threadIdx.x == 255) bsum[blockIdx.x] = s[255];
}

__global__ void scan_top(unsigned* __restrict__ bsum, int nb) {
    if (threadIdx.x == 0 && blockIdx.x == 0) {
        unsigned acc = 0;
        for (int i = 0; i < nb; ++i) { unsigned t = bsum[i]; bsum[i] = acc; acc += t; }
    }
}

__global__ void add_off(unsigned* __restrict__ hist, const unsigned* __restrict__ bsum, int N) {
    int i = blockIdx.x * 256 + threadIdx.x;
    if (i < N) hist[i] += bsum[blockIdx.x];
}

__global__ void sort2_kernel(const int* __restrict__ col, const unsigned* __restrict__ hist,
                             const unsigned* __restrict__ epos, unsigned* __restrict__ perm,
                             int E) {
    int e = blockIdx.x * 256 + threadIdx.x;
    if (e < E) perm[hist[col[e]] + epos[e]] = (unsigned)e;
}

// ---------------------------------------------------------------------------
// Pass 1: scatter edge_vec sums + counts (atomics; small L2-resident region)
// ---------------------------------------------------------------------------
__global__ void scatter_vec_kernel(const int* __restrict__ col,
                                   const float* __restrict__ edge_vec,
                                   float* __restrict__ vec_sum,
                                   float* __restrict__ counts, int E) {
    int e = blockIdx.x * blockDim.x + threadIdx.x;
    if (e >= E) return;
    int c = col[e];
    atomicAdd(&vec_sum[(size_t)c * 3 + 0], edge_vec[(size_t)e * 3 + 0]);
    atomicAdd(&vec_sum[(size_t)c * 3 + 1], edge_vec[(size_t)e * 3 + 1]);
    atomicAdd(&vec_sum[(size_t)c * 3 + 2], edge_vec[(size_t)e * 3 + 2]);
    atomicAdd(&counts[c], 1.0f);
}

// ---------------------------------------------------------------------------
// Pass 2: fused edge pipeline on SORTED edges, fp16 MFMA (fp32 accumulate).
// 512 threads = 8 waves. wave w: m16 = w>>1 (16 sorted positions), nh = w&1.
// After layer 4, gated messages land in an LDS f32 tile; a segmented scan
// over the sorted cols emits one atomicAdd per (col-run x column).
// ---------------------------------------------------------------------------
__global__ __launch_bounds__(512, 4)
void edge_mfma(const _Float16* __restrict__ xb,
               const int* __restrict__ ei,
               const unsigned* __restrict__ perm,
               const float* __restrict__ eattr,
               const float* __restrict__ evec,
               const float* __restrict__ elen,
               const _Float16* __restrict__ we1T, const float* __restrict__ e_b1,
               const _Float16* __restrict__ we2T, const float* __restrict__ e_b2,
               const _Float16* __restrict__ tw1T, const float* __restrict__ t_w1r,
               const float* __restrict__ t_b1,
               const _Float16* __restrict__ tw2T, const float* __restrict__ t_b2,
               const float* __restrict__ vec_sum, const float* __restrict__ counts,
               float* __restrict__ aggr, int E) {
    __shared__ _Float16 sh[ET][DIM + 8];   // activation relay, padded (272B row)
    __shared__ float msgf[ET][DIM + 4];    // gated messages f32 (132-f stride: 2-way banks)
    __shared__ float s_cos[ET];
    __shared__ int s_col[ET];

    const int tid = threadIdx.x;
    const int eb = blockIdx.x * ET;
    const int wid = tid >> 6, lane = tid & 63;
    const int lr = lane & 15, lk = lane >> 4;
    const int m16 = wid >> 1, nh = wid & 1;
    const int bcol = 64 * nh + lr;               // C/B col base; +16*j per n-tile
    const int rbase = 16 * m16 + 4 * lk;         // C row base; +r

    // --- stage cos_theta + sorted col indices (first 64 threads) ---
    if (tid < ET) {
        int ep = (int)perm[min(eb + tid, E - 1)];
        int c = ei[(size_t)E + ep];
        s_col[tid] = c;
        float cnt = fmaxf(counts[c], 1.0f);
        float vx = vec_sum[(size_t)c * 3 + 0] / cnt;
        float vy = vec_sum[(size_t)c * 3 + 1] / cnt;
        float vz = vec_sum[(size_t)c * 3 + 2] / cnt;
        float ex = evec[(size_t)ep * 3 + 0];
        float ey = evec[(size_t)ep * 3 + 1];
        float ez = evec[(size_t)ep * 3 + 2];
        float dot = ex * vx + ey * vy + ez * vz;
        float nrm = sqrtf(vx * vx + vy * vy + vz * vz);
        float ct = dot / (elen[ep] * (nrm + 1e-6f));
        s_cos[tid] = fminf(1.0f, fmaxf(-1.0f, ct));
    }

    // --- per-lane A-row pointers (sorted edge) ---
    const int ep = (int)perm[min(eb + 16 * m16 + lr, E - 1)];
    const int xr = ei[ep], xc = ei[(size_t)E + ep];
    const _Float16* pxr = xb + (size_t)xr * DIM + 8 * lk;
    const _Float16* pxc = xb + (size_t)xc * DIM + 8 * lk;
    const float* pat = eattr + (size_t)ep * NRBF + 8 * lk;

    const f32x4 zero = {0.f, 0.f, 0.f, 0.f};

    // ---- layer 1: [64x320] @ e_w1 -> swish ----
    f32x4 acc[4] = {zero, zero, zero, zero};
#pragma unroll
    for (int kt = 0; kt < 10; ++kt) {
        f16x8 a;
        if (kt < 4) {
            a = *(const f16x8*)(pxr + 32 * kt);
        } else if (kt < 6) {
            float4 f0 = *(const float4*)(pat + 32 * (kt - 4));
            float4 f1 = *(const float4*)(pat + 32 * (kt - 4) + 4);
            a = cvt8(f0, f1);
        } else {
            a = *(const f16x8*)(pxc + 32 * (kt - 6));
        }
#pragma unroll
        for (int j = 0; j < 4; ++j) {
            f16x8 b = *(const f16x8*)(we1T + (size_t)(bcol + 16 * j) * K1 + 32 * kt + 8 * lk);
            acc[j] = __builtin_amdgcn_mfma_f32_16x16x32_f16(a, b, acc[j], 0, 0, 0);
        }
    }
#pragma unroll
    for (int j = 0; j < 4; ++j) {
        float bv = e_b1[bcol + 16 * j];
#pragma unroll
        for (int r = 0; r < 4; ++r)
            sh[rbase + r][bcol + 16 * j] = (_Float16)swishf_(acc[j][r] + bv);
    }
    __syncthreads();

    // ---- layer 2: h1 @ e_w2 -> swish = m (keep f32 in regs, f16 in LDS) ----
    f32x4 acc2[4] = {zero, zero, zero, zero};
#pragma unroll
    for (int kt = 0; kt < 4; ++kt) {
        f16x8 a = *(const f16x8*)(&sh[16 * m16 + lr][32 * kt + 8 * lk]);
#pragma unroll
        for (int j = 0; j < 4; ++j) {
            f16x8 b = *(const f16x8*)(we2T + (size_t)(bcol + 16 * j) * DIM + 32 * kt + 8 * lk);
            acc2[j] = __builtin_amdgcn_mfma_f32_16x16x32_f16(a, b, acc2[j], 0, 0, 0);
        }
    }
    __syncthreads();
    float m_[4][4];
#pragma unroll
    for (int j = 0; j < 4; ++j) {
        float bv = e_b2[bcol + 16 * j];
#pragma unroll
        for (int r = 0; r < 4; ++r) {
            float mm = swishf_(acc2[j][r] + bv);
            m_[j][r] = mm;
            sh[rbase + r][bcol + 16 * j] = (_Float16)mm;
        }
    }
    __syncthreads();

    // ---- layer 3: [m | cos] @ t_w1 -> swish ----
    f32x4 acc3[4] = {zero, zero, zero, zero};
#pragma unroll
    for (int kt = 0; kt < 4; ++kt) {
        f16x8 a = *(const f16x8*)(&sh[16 * m16 + lr][32 * kt + 8 * lk]);
#pragma unroll
        for (int j = 0; j < 4; ++j) {
            f16x8 b = *(const f16x8*)(tw1T + (size_t)(bcol + 16 * j) * DIM + 32 * kt + 8 * lk);
            acc3[j] = __builtin_amdgcn_mfma_f32_16x16x32_f16(a, b, acc3[j], 0, 0, 0);
        }
    }
    __syncthreads();
#pragma unroll
    for (int j = 0; j < 4; ++j) {
        float bv = t_b1[bcol + 16 * j];
        float wr = t_w1r[bcol + 16 * j];   // t_w1 row 128 (cos column)
#pragma unroll
        for (int r = 0; r < 4; ++r) {
            float ct = s_cos[rbase + r];
            sh[rbase + r][bcol + 16 * j] = (_Float16)swishf_(acc3[j][r] + ct * wr + bv);
        }
    }
    __syncthreads();

    // ---- layer 4: h2 @ t_w2 -> sigmoid -> gate -> LDS msg tile ----
    f32x4 acc4[4] = {zero, zero, zero, zero};
#pragma unroll
    for (int kt = 0; kt < 4; ++kt) {
        f16x8 a = *(const f16x8*)(&sh[16 * m16 + lr][32 * kt + 8 * lk]);
#pragma unroll
        for (int j = 0; j < 4; ++j) {
            f16x8 b = *(const f16x8*)(tw2T + (size_t)(bcol + 16 * j) * DIM + 32 * kt + 8 * lk);
            acc4[j] = __builtin_amdgcn_mfma_f32_16x16x32_f16(a, b, acc4[j], 0, 0, 0);
        }
    }
#pragma unroll
    for (int j = 0; j < 4; ++j) {
        float bv = t_b2[bcol + 16 * j];
#pragma unroll
        for (int r = 0; r < 4; ++r) {
            int rowE = rbase + r;
            float v = 0.0f;
            if (eb + rowE < E) v = m_[j][r] * sigmoidf_(acc4[j][r] + bv);
            msgf[rowE][bcol + 16 * j] = v;
        }
    }
    __syncthreads();

    // ---- segmented reduction over sorted cols: one atomic per col-run ----
    {
        const int c = tid & 127;      // output column
        const int g = tid >> 7;       // row-group 0..3 (16 rows each)
        int prev = s_col[16 * g];
        float run = 0.0f;
#pragma unroll
        for (int i = 0; i < 16; ++i) {
            int row = 16 * g + i;
            int cc = s_col[row];
            if (cc != prev) {
                atomicAdd(&aggr[(size_t)prev * DIM + c], run);
                run = 0.0f;
                prev = cc;
            }
            run += msgf[row][c];
        }
        atomicAdd(&aggr[(size_t)prev * DIM + c], run);
    }
}

// ---------------------------------------------------------------------------
// Pass 3: node MLP on [x | aggr] + residual, fp16 MFMA.
// ---------------------------------------------------------------------------
__global__ __launch_bounds__(512, 4)
void node_mfma(const _Float16* __restrict__ xb, const float* __restrict__ x,
               const float* __restrict__ aggr,
               const _Float16* __restrict__ nw1T, const float* __restrict__ n_b1,
               const _Float16* __restrict__ nw2T, const float* __restrict__ n_b2,
               float* __restrict__ out, int N) {
    __shared__ _Float16 sh[NT][DIM + 8];

    const int tid = threadIdx.x;
    const int nb = blockIdx.x * NT;
    const int wid = tid >> 6, lane = tid & 63;
    const int lr = lane & 15, lk = lane >> 4;
    const int m16 = wid >> 1, nh = wid & 1;
    const int bcol = 64 * nh + lr;
    const int rbase = 16 * m16 + 4 * lk;

    const int nrow = min(nb + 16 * m16 + lr, N - 1);
    const _Float16* px = xb + (size_t)nrow * DIM + 8 * lk;
    const float* pa = aggr + (size_t)nrow * DIM + 8 * lk;

    const f32x4 zero = {0.f, 0.f, 0.f, 0.f};

    // ---- layer 1: [64x256] @ n_w1 -> swish ----
    f32x4 acc[4] = {zero, zero, zero, zero};
#pragma unroll
    for (int kt = 0; kt < 8; ++kt) {
        f16x8 a;
        if (kt < 4) {
            a = *(const f16x8*)(px + 32 * kt);
        } else {
            float4 f0 = *(const float4*)(pa + 32 * (kt - 4));
            float4 f1 = *(const float4*)(pa + 32 * (kt - 4) + 4);
            a = cvt8(f0, f1);
        }
#pragma unroll
        for (int j = 0; j < 4; ++j) {
            f16x8 b = *(const f16x8*)(nw1T + (size_t)(bcol + 16 * j) * 256 + 32 * kt + 8 * lk);
            acc[j] = __builtin_amdgcn_mfma_f32_16x16x32_f16(a, b, acc[j], 0, 0, 0);
        }
    }
#pragma unroll
    for (int j = 0; j < 4; ++j) {
        float bv = n_b1[bcol + 16 * j];
#pragma unroll
        for (int r = 0; r < 4; ++r)
            sh[rbase + r][bcol + 16 * j] = (_Float16)swishf_(acc[j][r] + bv);
    }
    __syncthreads();

    // ---- layer 2: h1 @ n_w2 -> swish, + residual, store ----
    f32x4 acc2[4] = {zero, zero, zero, zero};
#pragma unroll
    for (int kt = 0; kt < 4; ++kt) {
        f16x8 a = *(const f16x8*)(&sh[16 * m16 + lr][32 * kt + 8 * lk]);
#pragma unroll
        for (int j = 0; j < 4; ++j) {
            f16x8 b = *(const f16x8*)(nw2T + (size_t)(bcol + 16 * j) * DIM + 32 * kt + 8 * lk);
            acc2[j] = __builtin_amdgcn_mfma_f32_16x16x32_f16(a, b, acc2[j], 0, 0, 0);
        }
    }
#pragma unroll
    for (int j = 0; j < 4; ++j) {
        float bv = n_b2[bcol + 16 * j];
#pragma unroll
        for (int r = 0; r < 4; ++r) {
            int row = nb + rbase + r;
            if (row < N) {
                int col = bcol + 16 * j;
                out[(size_t)row * DIM + col] =
                    x[(size_t)row * DIM + col] + swishf_(acc2[j][r] + bv);
            }
        }
    }
}

// ---------------------------------------------------------------------------
extern "C" void kernel_launch(void* const* d_in, const int* in_sizes, int n_in,
                              void* d_out, int out_size, void* d_ws, size_t ws_size,
                              hipStream_t stream) {
    const float* x           = (const float*)d_in[0];
    const int*   edge_index  = (const int*)d_in[1];
    const float* edge_attr   = (const float*)d_in[2];
    const float* edge_vec    = (const float*)d_in[3];
    const float* edge_length = (const float*)d_in[4];
    const float* e_w1 = (const float*)d_in[5];
    const float* e_b1 = (const float*)d_in[6];
    const float* e_w2 = (const float*)d_in[7];
    const float* e_b2 = (const float*)d_in[8];
    const float* n_w1 = (const float*)d_in[9];
    const float* n_b1 = (const float*)d_in[10];
    const float* n_w2 = (const float*)d_in[11];
    const float* n_b2 = (const float*)d_in[12];
    const float* t_w1 = (const float*)d_in[13];
    const float* t_b1 = (const float*)d_in[14];
    const float* t_w2 = (const float*)d_in[15];
    const float* t_b2 = (const float*)d_in[16];
    float* out = (float*)d_out;

    const int N = in_sizes[0] / DIM;
    const int E = in_sizes[4];
    const int* col = edge_index + E;

    // workspace layout
    float* aggr    = (float*)d_ws;                       // N*128 f32
    float* vec_sum = aggr + (size_t)N * DIM;             // N*3
    float* counts  = vec_sum + (size_t)N * 3;            // N
    _Float16* xb   = (_Float16*)(counts + N);            // N*128 f16
    _Float16* we1T = xb + (size_t)N * DIM;               // 128*320
    _Float16* we2T = we1T + 128 * K1;                    // 128*128
    _Float16* tw1T = we2T + 128 * DIM;                   // 128*128
    _Float16* tw2T = tw1T + 128 * DIM;                   // 128*128
    _Float16* nw1T = tw2T + 128 * DIM;                   // 128*256
    _Float16* nw2T = nw1T + 128 * 256;                   // 128*128
    unsigned* perm = (unsigned*)(nw2T + 128 * DIM);      // E u32
    const float* t_w1r = t_w1 + (size_t)DIM * DIM;       // row 128 of t_w1

    // sort scratch aliased into aggr region (sort completes before aggr memset)
    unsigned* epos = (unsigned*)aggr;                    // E u32
    unsigned* hist = epos + E;                           // N u32
    unsigned* bsum = hist + N;                           // ~512 u32

    const int nbScan = (N + 255) / 256;

    // ---- counting sort of edges by col ----
    hipMemsetAsync(hist, 0, (size_t)N * sizeof(unsigned), stream);
    hist_kernel<<<(E + 255) / 256, 256, 0, stream>>>(col, hist, epos, E);
    scan_blocks<<<nbScan, 256, 0, stream>>>(hist, bsum, N);
    scan_top<<<1, 64, 0, stream>>>(bsum, nbScan);
    add_off<<<nbScan, 256, 0, stream>>>(hist, bsum, N);
    sort2_kernel<<<(E + 255) / 256, 256, 0, stream>>>(col, hist, epos, perm, E);

    // ---- zero accumulators (after sort scratch is dead) ----
    hipMemsetAsync(aggr, 0, (size_t)N * (DIM + 4) * sizeof(float), stream);

    // ---- prep: conversions + transposes ----
    {
        int n8 = N * DIM / 8;
        cvt_x_kernel<<<(n8 + 255) / 256, 256, 0, stream>>>(x, xb, n8);
        wT_kernel<<<dim3(5, 128), 64, 0, stream>>>(e_w1, we1T, K1);
        wT_kernel<<<dim3(2, 128), 64, 0, stream>>>(e_w2, we2T, DIM);
        wT_kernel<<<dim3(2, 128), 64, 0, stream>>>(t_w1, tw1T, DIM);  // rows 0..127
        wT_kernel<<<dim3(2, 128), 64, 0, stream>>>(t_w2, tw2T, DIM);
        wT_kernel<<<dim3(4, 128), 64, 0, stream>>>(n_w1, nw1T, 256);
        wT_kernel<<<dim3(2, 128), 64, 0, stream>>>(n_w2, nw2T, DIM);
    }

    scatter_vec_kernel<<<(E + 255) / 256, 256, 0, stream>>>(
        col, edge_vec, vec_sum, counts, E);

    edge_mfma<<<(E + ET - 1) / ET, 512, 0, stream>>>(
        xb, edge_index, perm, edge_attr, edge_vec, edge_length,
        we1T, e_b1, we2T, e_b2, tw1T, t_w1r, t_b1, tw2T, t_b2,
        vec_sum, counts, aggr, E);

    node_mfma<<<(N + NT - 1) / NT, 512, 0, stream>>>(
        xb, x, aggr, nw1T, n_b1, nw2T, n_b2, out, N);
}